// Round 1
// baseline (43146.918 us; speedup 1.0000x reference)
//
#include <hip/hip_runtime.h>

#define T_TOTAL 8000

__device__ __forceinline__ float sig_f(float x) { return 1.f / (1.f + __expf(-x)); }
__device__ __forceinline__ float tanh_f(float x) { return 1.f - 2.f / (__expf(2.f * x) + 1.f); }

// ---------------- init: unpack states, zero flags ----------------
__global__ void init_kernel(const float* __restrict__ st, float* hg, float* cs, unsigned* fl) {
  int idx = blockIdx.x * blockDim.x + threadIdx.x;
  if (idx < 2048) {           // p*512+u
    hg[idx] = st[2 * idx + 0];   // h0 into buffer 0
    cs[idx] = st[2 * idx + 1];
  }
  if (idx < 256) fl[idx] = 0u;  // 4 passes x 64 producer-waves (ws poisoned -> MUST clear)
}

// ---------------- projection: xz[p][t][2048] = x_p @ W_p + b_p ----------------
__global__ __launch_bounds__(256) void proj_kernel(
    const float* __restrict__ in_real, const float* __restrict__ in_imag,
    const float* __restrict__ Wr, const float* __restrict__ br,
    const float* __restrict__ Wi, const float* __restrict__ bi,
    float* __restrict__ xz, int t0, int chunk) {
  const int p = blockIdx.z;
  const float* __restrict__ X = (p < 2) ? in_real : in_imag;
  const float* __restrict__ W = (p & 1) ? Wi : Wr;
  const float* __restrict__ Bv = (p & 1) ? bi : br;
  const int nb = blockIdx.x * 64, mb = blockIdx.y * 64;
  __shared__ float As[16][68];
  __shared__ float Bs[16][68];
  const int tid = threadIdx.x;
  const int tm = tid >> 4, tn = tid & 15;
  const int lam = tid >> 2, lak = (tid & 3) << 2;   // A: row, k-offset
  const int lbk = tid >> 4, lbn = (tid & 15) << 2;  // B: k, col-offset
  float acc[4][4] = {};
  for (int k0 = 0; k0 < 512; k0 += 16) {
    int msafe = mb + lam; if (msafe > chunk - 1) msafe = chunk - 1;
    float4 a4 = *(const float4*)&X[(size_t)(t0 + msafe) * 512 + k0 + lak];
    float4 b4 = *(const float4*)&W[(size_t)(k0 + lbk) * 2048 + nb + lbn];
    __syncthreads();
    As[lak + 0][lam] = a4.x; As[lak + 1][lam] = a4.y;
    As[lak + 2][lam] = a4.z; As[lak + 3][lam] = a4.w;
    *(float4*)&Bs[lbk][lbn] = b4;
    __syncthreads();
#pragma unroll
    for (int k = 0; k < 16; ++k) {
      float4 av = *(const float4*)&As[k][tm << 2];
      float4 bv = *(const float4*)&Bs[k][tn << 2];
      acc[0][0] = fmaf(av.x, bv.x, acc[0][0]); acc[0][1] = fmaf(av.x, bv.y, acc[0][1]);
      acc[0][2] = fmaf(av.x, bv.z, acc[0][2]); acc[0][3] = fmaf(av.x, bv.w, acc[0][3]);
      acc[1][0] = fmaf(av.y, bv.x, acc[1][0]); acc[1][1] = fmaf(av.y, bv.y, acc[1][1]);
      acc[1][2] = fmaf(av.y, bv.z, acc[1][2]); acc[1][3] = fmaf(av.y, bv.w, acc[1][3]);
      acc[2][0] = fmaf(av.z, bv.x, acc[2][0]); acc[2][1] = fmaf(av.z, bv.y, acc[2][1]);
      acc[2][2] = fmaf(av.z, bv.z, acc[2][2]); acc[2][3] = fmaf(av.z, bv.w, acc[2][3]);
      acc[3][0] = fmaf(av.w, bv.x, acc[3][0]); acc[3][1] = fmaf(av.w, bv.y, acc[3][1]);
      acc[3][2] = fmaf(av.w, bv.z, acc[3][2]); acc[3][3] = fmaf(av.w, bv.w, acc[3][3]);
    }
  }
  float4 bias4 = *(const float4*)&Bv[nb + (tn << 2)];
#pragma unroll
  for (int i = 0; i < 4; ++i) {
    int mm = mb + (tm << 2) + i;
    if (mm < chunk) {
      float4 v;
      v.x = acc[i][0] + bias4.x; v.y = acc[i][1] + bias4.y;
      v.z = acc[i][2] + bias4.z; v.w = acc[i][3] + bias4.w;
      *(float4*)&xz[(size_t)(p * chunk + mm) * 2048 + nb + (tn << 2)] = v;
    }
  }
}

// ---------------- persistent recurrent kernel (wave-autonomous) ----------------
// grid = 64 blocks x 256 threads, 1 WG/CU (~290 VGPR). Block: pass p=(bx&7)>>1
// (pass -> one XCD pair if dispatch round-robins bx%8), wg=((bx>>3)<<1)|(bx&1) in [0,16).
// Each WAVE independently owns 8 units x full K=512: lane = (u=l&7, kg=l>>3),
// holds R[kg*64..+64][gate*512+U0+u] in 256 VGPRs. No __syncthreads in the loop.
// Cross-WG exchange: agent-scope relaxed atomics (cache-bypass) for h + per-wave
// flags; ordering h-store -> flag via counted s_waitcnt vmcnt(4). No acquire/release
// fences -> no buffer_inv / buffer_wbl2 on the critical path, L2 stays warm for xz.
__global__ __launch_bounds__(256, 1) void recur_kernel(
    const float* __restrict__ xz, const float* __restrict__ Rr, const float* __restrict__ Ri,
    float* hg, float* cs, unsigned* fl_base, float* out, int t0, int chunk) {
  const int tid = threadIdx.x;
  const int w = tid >> 6, l = tid & 63;
  const int u = l & 7, kg = l >> 3;
  const int bx = blockIdx.x;
  const int p = (bx & 7) >> 1;
  const int wg = ((bx >> 3) << 1) | (bx & 1);
  const int U0 = wg * 32 + w * 8;
  const float* __restrict__ R = (p & 1) ? Ri : Rr;

  // R slice -> 256 VGPRs (one-time per launch)
  float r[4][64];
  {
    const float* Rb = R + (size_t)(kg * 64) * 2048 + (U0 + u);
#pragma unroll
    for (int kk = 0; kk < 64; ++kk) {
#pragma unroll
      for (int gg = 0; gg < 4; ++gg) r[gg][kk] = Rb[(size_t)kk * 2048 + gg * 512];
    }
  }

  // wave-private skewed LDS h-stage: float j of window kg lives at [kg*68 + j]
  // (16B skew per kg => ds_read_b128 banks 4*kg..4*kg+3, conflict-free broadcast)
  __shared__ float hsh[4][580];
  float* wp = &hsh[w][l * 8 + kg * 4];
  const float* rp = &hsh[w][kg * 68];

  unsigned* flp = fl_base + p * 64;          // 64 producer-wave flags per pass
  const int myflag = wg * 4 + w;
  float c_old = cs[p * 512 + U0 + u];        // replicated across kg lanes

  float xzv[4];
  {
    const float* xr = xz + ((size_t)p * chunk + 0) * 2048 + (U0 + u);
#pragma unroll
    for (int gg = 0; gg < 4; ++gg) xzv[gg] = xr[gg * 512];
  }

#pragma unroll 1
  for (int tl = 0; tl < chunk; ++tl) {
    const int t = t0 + tl;
    // wait: all 64 producer-waves of this pass finished step t-1 (flag >= t)
    {
      const unsigned tgt = (unsigned)t;
      for (;;) {
        unsigned v = __hip_atomic_load(&flp[l], __ATOMIC_RELAXED, __HIP_MEMORY_SCOPE_AGENT);
        if (__all(v >= tgt)) break;
        __builtin_amdgcn_s_sleep(1);
      }
    }
    asm volatile("" ::: "memory");  // pin h loads below the poll (issue is in-order per wave)

    // coherent gather of h(t-1): lane loads 32B (4x8B agent atomics) -> LDS
    {
      const float* hsrc = hg + ((t & 1) * 2048 + p * 512) + 8 * l;
      const unsigned long long* h8 = (const unsigned long long*)hsrc;
      unsigned long long q0 = __hip_atomic_load(h8 + 0, __ATOMIC_RELAXED, __HIP_MEMORY_SCOPE_AGENT);
      unsigned long long q1 = __hip_atomic_load(h8 + 1, __ATOMIC_RELAXED, __HIP_MEMORY_SCOPE_AGENT);
      unsigned long long q2 = __hip_atomic_load(h8 + 2, __ATOMIC_RELAXED, __HIP_MEMORY_SCOPE_AGENT);
      unsigned long long q3 = __hip_atomic_load(h8 + 3, __ATOMIC_RELAXED, __HIP_MEMORY_SCOPE_AGENT);
      union U8 { unsigned long long v; float2 f; };
      U8 c0, c1, c2, c3; c0.v = q0; c1.v = q1; c2.v = q2; c3.v = q3;
      float4 w0 = make_float4(c0.f.x, c0.f.y, c1.f.x, c1.f.y);
      float4 w1 = make_float4(c2.f.x, c2.f.y, c3.f.x, c3.f.y);
      *(float4*)wp = w0;
      *(float4*)(wp + 4) = w1;
    }

    // GEMV: 64-k window for unit u, 4 gates (256 fma) out of LDS broadcast reads
    float a[4] = {0.f, 0.f, 0.f, 0.f};
#pragma unroll
    for (int q = 0; q < 16; ++q) {
      float4 h4 = *(const float4*)(rp + 4 * q);
#pragma unroll
      for (int gg = 0; gg < 4; ++gg) {
        a[gg] = fmaf(r[gg][4 * q + 0], h4.x, a[gg]);
        a[gg] = fmaf(r[gg][4 * q + 1], h4.y, a[gg]);
        a[gg] = fmaf(r[gg][4 * q + 2], h4.z, a[gg]);
        a[gg] = fmaf(r[gg][4 * q + 3], h4.w, a[gg]);
      }
    }
    // reduce over the 8 k-groups (lane bits 3,4,5) -> every lane has full z
#pragma unroll
    for (int gg = 0; gg < 4; ++gg) {
      a[gg] += __shfl_xor(a[gg], 8);
      a[gg] += __shfl_xor(a[gg], 16);
      a[gg] += __shfl_xor(a[gg], 32);
    }
    const float zi = a[0] + xzv[0], zf = a[1] + xzv[1];
    const float zg = a[2] + xzv[2], zo = a[3] + xzv[3];
    const float cn = sig_f(zf) * c_old + sig_f(zi) * tanh_f(zg);
    const float hn = sig_f(zo) * tanh_f(cn);
    c_old = cn;  // replicated identically across kg lanes

    // publish: out atomic (1 VMEM) + h store (1 VMEM), then 4 xz loads, then
    // vmcnt(4): in-order retirement guarantees out+h done, xz still in flight.
    float* hdst = hg + (((t + 1) & 1) * 2048 + p * 512);
    if (l < 8) {
      const size_t oidx = (size_t)t * 512 + U0 + l;
      if (p == 0)      atomicAdd(&out[oidx], hn);                    // real += r2r
      else if (p == 3) atomicAdd(&out[oidx], -hn);                   // real -= i2i
      else             atomicAdd(&out[(size_t)4096000 + oidx], hn);  // imag += r2i/i2r
      __hip_atomic_store(hdst + U0 + l, hn, __ATOMIC_RELAXED, __HIP_MEMORY_SCOPE_AGENT);
    }
    asm volatile("" ::: "memory");  // pin xz loads after h store
    {
      const int tn2 = (tl + 1 < chunk) ? tl + 1 : tl;  // tail: harmless re-read
      const float* xr = xz + ((size_t)p * chunk + tn2) * 2048 + (U0 + u);
#pragma unroll
      for (int gg = 0; gg < 4; ++gg) xzv[gg] = xr[gg * 512];
    }
    asm volatile("s_waitcnt vmcnt(4)" ::: "memory");  // h-store acked at coherence point
    if (l == 0)
      __hip_atomic_store(&flp[myflag], (unsigned)(t + 1), __ATOMIC_RELAXED, __HIP_MEMORY_SCOPE_AGENT);
    if (t == T_TOTAL - 1 && l < 8) {
      const size_t myu = (size_t)p * 512 + U0 + l;
      out[8192000 + 2 * myu + 0] = hn;
      out[8192000 + 2 * myu + 1] = cn;
    }
  }
  if (l < 8) cs[p * 512 + U0 + l] = c_old;
}

extern "C" void kernel_launch(void* const* d_in, const int* in_sizes, int n_in,
                              void* d_out, int out_size, void* d_ws, size_t ws_size,
                              hipStream_t stream) {
  (void)in_sizes; (void)n_in;
  const float* in_real   = (const float*)d_in[0];
  const float* in_imag   = (const float*)d_in[1];
  const float* in_states = (const float*)d_in[2];
  const float* Wr = (const float*)d_in[3];
  const float* Rr = (const float*)d_in[4];
  const float* br = (const float*)d_in[5];
  const float* Wi = (const float*)d_in[6];
  const float* Ri = (const float*)d_in[7];
  const float* bi = (const float*)d_in[8];
  float* out = (float*)d_out;

  // ws layout: h double-buffer [2][4][512] | c [4][512] | flags [256] | pad to 64KB | xz chunk
  float* hg = (float*)d_ws;
  float* cs = hg + 2 * 2048;
  unsigned* fl = (unsigned*)(cs + 2048);
  float* xz = (float*)((char*)d_ws + 65536);

  int chunk = 2000;  // halvings all divide 8000
  while (chunk > 125 && (size_t)chunk * 4 * 2048 * sizeof(float) + 65536 > ws_size) chunk >>= 1;

  hipMemsetAsync(d_out, 0, (size_t)out_size * sizeof(float), stream);
  init_kernel<<<2, 1024, 0, stream>>>(in_states, hg, cs, fl);
  for (int t0 = 0; t0 < T_TOTAL; t0 += chunk) {
    dim3 pgrid(2048 / 64, (chunk + 63) / 64, 4);
    proj_kernel<<<pgrid, 256, 0, stream>>>(in_real, in_imag, Wr, br, Wi, bi, xz, t0, chunk);
    recur_kernel<<<64, 256, 0, stream>>>(xz, Rr, Ri, hg, cs, fl, out, t0, chunk);
  }
}

// Round 2
// 20751.605 us; speedup vs baseline: 2.0792x; 2.0792x over previous
//
#include <hip/hip_runtime.h>

#define T_TOTAL 8000
#define UDIM 512
#define NG 2048
#define GWG 32   // workgroups per pass
#define NUW 16   // LSTM units per workgroup

__device__ __forceinline__ float sig_f(float x) { return 1.f / (1.f + __expf(-x)); }
__device__ __forceinline__ float tanh_f(float x) { return 1.f - 2.f / (__expf(2.f * x) + 1.f); }

// ---------------- init: unpack states, zero flags ----------------
__global__ void init_kernel(const float* __restrict__ st, float* hg, float* cs, unsigned* fl) {
  int idx = blockIdx.x * blockDim.x + threadIdx.x;
  if (idx < 2048) {           // p*512+u
    hg[idx] = st[2 * idx + 0];   // h0 into buffer 0
    cs[idx] = st[2 * idx + 1];
  }
  if (idx < 128) fl[idx] = 0u;  // 4 passes x 32 WGs  (MUST clear: ws poisoned 0xAA)
}

// ---------------- projection: xz[p][t][2048] = x_p @ W_p + b_p ----------------
__global__ __launch_bounds__(256) void proj_kernel(
    const float* __restrict__ in_real, const float* __restrict__ in_imag,
    const float* __restrict__ Wr, const float* __restrict__ br,
    const float* __restrict__ Wi, const float* __restrict__ bi,
    float* __restrict__ xz, int t0, int chunk) {
  const int p = blockIdx.z;
  const float* __restrict__ X = (p < 2) ? in_real : in_imag;
  const float* __restrict__ W = (p & 1) ? Wi : Wr;
  const float* __restrict__ Bv = (p & 1) ? bi : br;
  const int nb = blockIdx.x * 64, mb = blockIdx.y * 64;
  __shared__ float As[16][68];
  __shared__ float Bs[16][68];
  const int tid = threadIdx.x;
  const int tm = tid >> 4, tn = tid & 15;
  const int lam = tid >> 2, lak = (tid & 3) << 2;   // A: row, k-offset
  const int lbk = tid >> 4, lbn = (tid & 15) << 2;  // B: k, col-offset
  float acc[4][4] = {};
  for (int k0 = 0; k0 < 512; k0 += 16) {
    int msafe = mb + lam; if (msafe > chunk - 1) msafe = chunk - 1;
    float4 a4 = *(const float4*)&X[(size_t)(t0 + msafe) * 512 + k0 + lak];
    float4 b4 = *(const float4*)&W[(size_t)(k0 + lbk) * 2048 + nb + lbn];
    __syncthreads();
    As[lak + 0][lam] = a4.x; As[lak + 1][lam] = a4.y;
    As[lak + 2][lam] = a4.z; As[lak + 3][lam] = a4.w;
    *(float4*)&Bs[lbk][lbn] = b4;
    __syncthreads();
#pragma unroll
    for (int k = 0; k < 16; ++k) {
      float4 av = *(const float4*)&As[k][tm << 2];
      float4 bv = *(const float4*)&Bs[k][tn << 2];
      acc[0][0] = fmaf(av.x, bv.x, acc[0][0]); acc[0][1] = fmaf(av.x, bv.y, acc[0][1]);
      acc[0][2] = fmaf(av.x, bv.z, acc[0][2]); acc[0][3] = fmaf(av.x, bv.w, acc[0][3]);
      acc[1][0] = fmaf(av.y, bv.x, acc[1][0]); acc[1][1] = fmaf(av.y, bv.y, acc[1][1]);
      acc[1][2] = fmaf(av.y, bv.z, acc[1][2]); acc[1][3] = fmaf(av.y, bv.w, acc[1][3]);
      acc[2][0] = fmaf(av.z, bv.x, acc[2][0]); acc[2][1] = fmaf(av.z, bv.y, acc[2][1]);
      acc[2][2] = fmaf(av.z, bv.z, acc[2][2]); acc[2][3] = fmaf(av.z, bv.w, acc[2][3]);
      acc[3][0] = fmaf(av.w, bv.x, acc[3][0]); acc[3][1] = fmaf(av.w, bv.y, acc[3][1]);
      acc[3][2] = fmaf(av.w, bv.z, acc[3][2]); acc[3][3] = fmaf(av.w, bv.w, acc[3][3]);
    }
  }
  float4 bias4 = *(const float4*)&Bv[nb + (tn << 2)];
#pragma unroll
  for (int i = 0; i < 4; ++i) {
    int mm = mb + (tm << 2) + i;
    if (mm < chunk) {
      float4 v;
      v.x = acc[i][0] + bias4.x; v.y = acc[i][1] + bias4.y;
      v.z = acc[i][2] + bias4.z; v.w = acc[i][3] + bias4.w;
      *(float4*)&xz[(size_t)(p * chunk + mm) * 2048 + nb + (tn << 2)] = v;
    }
  }
}

// ---------------- persistent recurrent kernel ----------------
// grid = 128 blocks (<= 256 CUs -> all co-resident, no deadlock), 256 threads.
// block: pass p = bx&3, slice g = bx>>2. Owns units [g*16, g*16+16).
// thread (wave w, lane l): k-range = w*128 + (l>>4)*32 .. +32, unit uu = l&15;
// holds R[k][uu + 512*gate] for 4 gates in 128 VGPRs.
// Exchange (round-1-proven, fence-free): h travels via agent-scope relaxed
// atomic stores/loads (cache-bypass to the coherence point) -> no buffer_inv,
// no buffer_wbl2 on the critical path, L2 stays warm for xz.
// Ordering h-store -> flag-store via explicit s_waitcnt vmcnt(0).
// out atomicAdds (cross-XCD contended lines, ~900cy acks) moved AFTER the flag
// release: their completion overlaps the next inter-WG wait instead of gating it.
__global__ __launch_bounds__(256, 1) void recur_kernel(
    const float* __restrict__ xz, const float* __restrict__ Rr, const float* __restrict__ Ri,
    float* hg, float* cs, unsigned* fl_base, float* out, int t0, int chunk) {
  const int tid = threadIdx.x;
  const int w = tid >> 6, l = tid & 63;
  const int uu = l & 15, kg = l >> 4;
  const int p = blockIdx.x & 3, g = blockIdx.x >> 2;
  const int ubase = g * NUW;
  const float* __restrict__ R = (p & 1) ? Ri : Rr;
  const int kbase = w * 128 + kg * 32;

  // R slice -> registers (one-time, ~17 MB total reads)
  float r[4][32];
#pragma unroll
  for (int kk = 0; kk < 32; ++kk) {
    const float* Rrow = R + (size_t)(kbase + kk) * 2048 + ubase + uu;
#pragma unroll
    for (int gg = 0; gg < 4; ++gg) r[gg][kk] = Rrow[gg * 512];
  }

  __shared__ float zpart[256];
  unsigned* fl = fl_base + p * 32;
  const int myu = p * 512 + ubase + uu;
  float c_old = 0.f;
  if (w == 0 && l < 16) c_old = cs[myu];
  // wave0 lane l computes z column: gate = l>>4, unit = ubase + (l&15)
  const size_t xzrowbase = (size_t)p * chunk * 2048 + (size_t)(ubase + uu) + ((size_t)kg << 9);

  for (int tl = 0; tl < chunk; ++tl) {
    const int t = t0 + tl;
    float xzv = 0.f;
    if (w == 0) xzv = xz[xzrowbase + (size_t)tl * 2048];  // pure input: issue before the spin
    if (w == 0) {
      const unsigned tgt = (unsigned)t;  // flag[g] == t+1 means WG g finished step t
      for (;;) {
        unsigned v = 0xFFFFFFFFu;
        if (l < 32) v = __hip_atomic_load(&fl[l], __ATOMIC_RELAXED, __HIP_MEMORY_SCOPE_AGENT);
        if (__all(v >= tgt)) break;
      }
    }
    __syncthreads();
    asm volatile("" ::: "memory");  // pin h gather below the rendezvous

    // GEMV: z_partial = h[t-1] (buffer t&1) dot R-slice
    // h gather: agent-scope relaxed atomic loads (bypass stale L1/L2; producers
    // stored h with agent atomics). 16x8B, broadcast addresses within kg group.
    float hv[32];
    {
      const unsigned long long* hp8 =
          (const unsigned long long*)(hg + ((t & 1) * 2048 + p * 512 + kbase));
#pragma unroll
      for (int q = 0; q < 16; ++q) {
        unsigned long long qv =
            __hip_atomic_load(hp8 + q, __ATOMIC_RELAXED, __HIP_MEMORY_SCOPE_AGENT);
        union { unsigned long long v; float2 f; } cv;
        cv.v = qv;
        hv[2 * q + 0] = cv.f.x;
        hv[2 * q + 1] = cv.f.y;
      }
    }
    float a[4] = {0.f, 0.f, 0.f, 0.f};
#pragma unroll
    for (int kk = 0; kk < 32; ++kk) {
#pragma unroll
      for (int gg = 0; gg < 4; ++gg) a[gg] = fmaf(r[gg][kk], hv[kk], a[gg]);
    }
    // reduce over the 4 k-groups within the wave (lanes xor 16, 32)
#pragma unroll
    for (int gg = 0; gg < 4; ++gg) {
      a[gg] += __shfl_xor(a[gg], 16);
      a[gg] += __shfl_xor(a[gg], 32);
    }
    if (l < 16) {
#pragma unroll
      for (int gg = 0; gg < 4; ++gg) zpart[w * 64 + gg * 16 + l] = a[gg];
    }
    __syncthreads();

    if (w == 0) {
      float z = zpart[l] + zpart[64 + l] + zpart[128 + l] + zpart[192 + l] + xzv;
      float zi = __shfl(z, uu);
      float zf = __shfl(z, uu + 16);
      float zg = __shfl(z, uu + 32);
      float zo = __shfl(z, uu + 48);
      float hn = 0.f, cn = 0.f;
      if (l < 16) {
        cn = sig_f(zf) * c_old + sig_f(zi) * tanh_f(zg);
        hn = sig_f(zo) * tanh_f(cn);
        c_old = cn;
        // h publish: agent atomic store (visible at coherence point, no wbl2)
        __hip_atomic_store(&hg[(((t + 1) & 1) * 2048) + p * 512 + ubase + l], hn,
                           __ATOMIC_RELAXED, __HIP_MEMORY_SCOPE_AGENT);
      }
      // order h-store before flag-store (stores ack in issue order at vmcnt)
      asm volatile("s_waitcnt vmcnt(0)" ::: "memory");
      if (l == 0)
        __hip_atomic_store(&fl[g], (unsigned)(t + 1), __ATOMIC_RELAXED,
                           __HIP_MEMORY_SCOPE_AGENT);
      // out writes AFTER the release: contended cross-XCD atomic acks overlap
      // the next inter-WG wait instead of sitting on the critical path.
      if (l < 16) {
        const size_t oidx = (size_t)t * 512 + ubase + l;
        if (p == 0)      atomicAdd(&out[oidx], hn);                      // real += r2r
        else if (p == 3) atomicAdd(&out[oidx], -hn);                     // real -= i2i
        else             atomicAdd(&out[(size_t)4096000 + oidx], hn);    // imag += r2i/i2r
        if (t == T_TOTAL - 1) {
          out[8192000 + 2 * (size_t)myu + 0] = hn;
          out[8192000 + 2 * (size_t)myu + 1] = cn;
        }
      }
    }
  }
  if (w == 0 && l < 16) cs[myu] = c_old;
}

extern "C" void kernel_launch(void* const* d_in, const int* in_sizes, int n_in,
                              void* d_out, int out_size, void* d_ws, size_t ws_size,
                              hipStream_t stream) {
  (void)in_sizes; (void)n_in;
  const float* in_real   = (const float*)d_in[0];
  const float* in_imag   = (const float*)d_in[1];
  const float* in_states = (const float*)d_in[2];
  const float* Wr = (const float*)d_in[3];
  const float* Rr = (const float*)d_in[4];
  const float* br = (const float*)d_in[5];
  const float* Wi = (const float*)d_in[6];
  const float* Ri = (const float*)d_in[7];
  const float* bi = (const float*)d_in[8];
  float* out = (float*)d_out;

  // ws layout: h double-buffer [2][4][512] | c [4][512] | flags [128] | pad to 64KB | xz chunk
  float* hg = (float*)d_ws;
  float* cs = hg + 2 * 2048;
  unsigned* fl = (unsigned*)(cs + 2048);
  float* xz = (float*)((char*)d_ws + 65536);

  int chunk = 2000;  // halvings all divide 8000
  while (chunk > 125 && (size_t)chunk * 4 * 2048 * sizeof(float) + 65536 > ws_size) chunk >>= 1;

  hipMemsetAsync(d_out, 0, (size_t)out_size * sizeof(float), stream);
  init_kernel<<<2, 1024, 0, stream>>>(in_states, hg, cs, fl);
  for (int t0 = 0; t0 < T_TOTAL; t0 += chunk) {
    dim3 pgrid(2048 / 64, (chunk + 63) / 64, 4);
    proj_kernel<<<pgrid, 256, 0, stream>>>(in_real, in_imag, Wr, br, Wi, bi, xz, t0, chunk);
    recur_kernel<<<4 * GWG, 256, 0, stream>>>(xz, Rr, Ri, hg, cs, fl, out, t0, chunk);
  }
}